// Round 3
// baseline (127.666 us; speedup 1.0000x reference)
//
#include <hip/hip_runtime.h>
#include <math.h>

#define BATCH   65536
#define N_IN    784
#define DD      10
#define NB      10
#define SD      100
#define N_OUTS  10

typedef float  f32x4  __attribute__((ext_vector_type(4)));
typedef short  bf16x8 __attribute__((ext_vector_type(8)));
typedef short  bf16x4 __attribute__((ext_vector_type(4)));

// ws layout (float offsets)
#define WT_F 0        // bf16 [112][800]  transposed, padded W_in        (44800 floats)
#define WD_F 44800    // bf16 [112 te][128 k] mask-folded W_data         (7168 floats)
#define BD_F 51968    // f32  [100]  bd_eff (te order)
#define WO_F 52068    // f32  [10][112] any_open-folded W_out, zero-pad  (1120 floats)
#define BL_F 53188    // f32  [10]   blog
#define MK_F 53198    // f32  [100]  mask (s*10+t)

__device__ __forceinline__ short f2bf(float f) {
    unsigned u = __builtin_bit_cast(unsigned, f);
    unsigned r = u + 0x7fffu + ((u >> 16) & 1u);   // RNE
    return (short)(r >> 16);
}

__device__ __forceinline__ bf16x8 pack8(float4 lo, float4 hi) {
    bf16x8 v;
    v[0] = f2bf(lo.x); v[1] = f2bf(lo.y); v[2] = f2bf(lo.z); v[3] = f2bf(lo.w);
    v[4] = f2bf(hi.x); v[5] = f2bf(hi.y); v[6] = f2bf(hi.z); v[7] = f2bf(hi.w);
    return v;
}

// ---------------- prep1: exact fp32 gating + small folded tables ----------------
__global__ void prep1_kernel(const float* __restrict__ x,
                             const float* __restrict__ W_in,
                             const float* __restrict__ b_in,
                             const float* __restrict__ W_gate,
                             const float* __restrict__ b_gate,
                             const float* __restrict__ b_data,
                             const float* __restrict__ W_out,
                             const float* __restrict__ b_out,
                             float* __restrict__ out,
                             float* __restrict__ ws) {
    __shared__ float a0r0[SD];
    __shared__ float mask_l[SD];
    __shared__ float ao_l[NB];
    const int tid = threadIdx.x;

    if (tid < SD) {                      // acts0 for batch row 0 (exact fp32)
        int s = tid / DD, d = tid % DD;
        float acc = b_in[tid];
        for (int i = 0; i < N_IN; ++i)
            acc += x[i] * W_in[s * (N_IN * DD) + i * DD + d];
        a0r0[tid] = fmaxf(acc, 0.f);
    }
    __syncthreads();

    if (tid < SD) {                      // gate[s][t] -> mask
        float g = b_gate[tid];
        int s = tid / DD;
        for (int d = 0; d < DD; ++d)
            g += a0r0[s * DD + d] * W_gate[tid * DD + d];
        mask_l[tid] = (g > 0.f) ? 1.f : 0.f;
    }
    __syncthreads();

    if (tid < NB) {
        float any = 0.f;
        for (int s = 0; s < NB; ++s) any = fmaxf(any, mask_l[s * DD + tid]);
        ao_l[tid] = any;
    }
    if (tid == 0) {
        float sum = 0.f;
        for (int i = 0; i < SD; ++i) sum += mask_l[i];
        out[(long)BATCH * N_OUTS] = sum / 20.0f;          // prob_open_gate
    }
    __syncthreads();

    if (tid < SD) ws[MK_F + tid] = mask_l[tid];

    // bd_eff[te] = sum_s mask[s,t] * b_data[s][t][e]
    if (tid < SD) {
        int t = tid / DD, e = tid % DD;
        float v = 0.f;
        for (int s = 0; s < NB; ++s)
            v += mask_l[s * DD + t] * b_data[(s * NB + t) * DD + e];
        ws[BD_F + tid] = v;
    }
    // Wo_eff[o][te] padded to [10][112]
    for (int idx = tid; idx < 10 * 112; idx += blockDim.x) {
        int o = idx / 112, te = idx % 112;
        float v = 0.f;
        if (te < SD) {
            int t = te / DD, e = te % DD;
            v = ao_l[t] * W_out[(t * DD + e) * N_OUTS + o];
        }
        ws[WO_F + idx] = v;
    }
    if (tid < N_OUTS) {
        float v = 0.f;
        for (int t = 0; t < NB; ++t) v += ao_l[t] * b_out[t * N_OUTS + tid];
        ws[BL_F + tid] = v;
    }
}

// ---------------- prep2: bf16 weight tables ----------------
__global__ void prep2_kernel(const float* __restrict__ W_in,
                             const float* __restrict__ W_data,
                             float* __restrict__ ws) {
    short* wt = (short*)(ws + WT_F);
    short* wd = (short*)(ws + WD_F);
    const float* mask = ws + MK_F;
    const int total = 112 * 800 + 112 * 128;
    for (int idx = blockIdx.x * blockDim.x + threadIdx.x; idx < total;
         idx += gridDim.x * blockDim.x) {
        if (idx < 112 * 800) {
            int c = idx / 800, k = idx % 800;
            float v = (c < SD && k < N_IN)
                          ? W_in[(c / DD) * (N_IN * DD) + k * DD + (c % DD)] : 0.f;
            wt[idx] = f2bf(v);
        } else {
            int i2 = idx - 112 * 800;
            int te = i2 / 128, k = i2 % 128;
            float v = 0.f;
            if (te < SD && k < SD) {
                int t = te / DD, e = te % DD, s = k / DD, d = k % DD;
                v = mask[s * DD + t] * W_data[((s * NB + t) * DD + d) * DD + e];
            }
            wd[i2] = f2bf(v);
        }
    }
}

// ---------------- main: MFMA phase2 (reg-pipelined x) + MFMA phase3a + VALU 3b ----------------
__global__ __launch_bounds__(256, 4) void main_kernel(
        const float* __restrict__ x,
        const float* __restrict__ b_in,
        const float* __restrict__ ws,
        float* __restrict__ out) {
    __shared__ __align__(16) short a0b[64 * 136];   // [64 rows][136 bf16] stride 272B

    const int tid  = threadIdx.x;
    const int w    = tid >> 6;
    const int lane = tid & 63;
    const int g    = lane >> 4;
    const int r    = lane & 15;
    const int lrow = w * 16 + r;
    const long grow = (long)blockIdx.x * 64 + lrow;

    const short* wt = (const short*)(ws + WT_F);
    const short* wd = (const short*)(ws + WD_F);

    // ---- phase 2: acts0 = relu(x @ Wt + b_in), MFMA 16x16x32, K pipelined ----
    f32x4 acc[7];
    #pragma unroll
    for (int ct = 0; ct < 7; ++ct) acc[ct] = (f32x4){0.f, 0.f, 0.f, 0.f};

    const float* xrow = x + grow * N_IN;
    const short* wtbase = wt + r * 800 + g * 8;

    float4 bufA[8], bufB[8];

    auto LOADC = [&](float4* buf, int c0) {
        #pragma unroll
        for (int p = 0; p < 4; ++p) {
            const float* a = xrow + (c0 + p) * 32 + g * 8;
            buf[2 * p]     = *(const float4*)(a);
            buf[2 * p + 1] = *(const float4*)(a + 4);
        }
    };
    auto COMPC = [&](const float4* buf, int c0) {
        #pragma unroll
        for (int p = 0; p < 4; ++p) {
            bf16x8 bfrag = pack8(buf[2 * p], buf[2 * p + 1]);
            #pragma unroll
            for (int ct = 0; ct < 7; ++ct) {
                bf16x8 afrag = *(const bf16x8*)(wtbase + ct * (16 * 800) + (c0 + p) * 32);
                acc[ct] = __builtin_amdgcn_mfma_f32_16x16x32_bf16(afrag, bfrag, acc[ct], 0, 0, 0);
            }
        }
    };

    // software pipeline: depth-2 register double buffer (all indices static)
    LOADC(bufA, 0);
    LOADC(bufB, 4);
    COMPC(bufA, 0);
    LOADC(bufA, 8);
    COMPC(bufB, 4);
    LOADC(bufB, 12);
    COMPC(bufA, 8);
    LOADC(bufA, 16);
    COMPC(bufB, 12);
    LOADC(bufB, 20);
    // tail loads (k0 = 768): x row only valid to k=783 -> g<2 only; Wt zero-padded past 784
    float4 tlo = make_float4(0.f, 0.f, 0.f, 0.f), thi = tlo;
    if (g < 2) {
        tlo = *(const float4*)(xrow + 768 + g * 8);
        thi = *(const float4*)(xrow + 768 + g * 8 + 4);
    }
    COMPC(bufA, 16);
    COMPC(bufB, 20);
    {
        bf16x8 bfrag = pack8(tlo, thi);
        #pragma unroll
        for (int ct = 0; ct < 7; ++ct) {
            bf16x8 afrag = *(const bf16x8*)(wtbase + ct * (16 * 800) + 768);
            acc[ct] = __builtin_amdgcn_mfma_f32_16x16x32_bf16(afrag, bfrag, acc[ct], 0, 0, 0);
        }
    }

    // bias + relu, write bf16 acts0 row to LDS (D layout: row=r, c=16ct+4g+j)
    short* myrow = a0b + lrow * 136;
    #pragma unroll
    for (int ct = 0; ct < 7; ++ct) {
        int c0 = 16 * ct + 4 * g;
        bf16x4 pk;
        #pragma unroll
        for (int j = 0; j < 4; ++j) {
            int c = c0 + j;
            float bias = (c < SD) ? b_in[c] : 0.f;
            pk[j] = f2bf(fmaxf(acc[ct][j] + bias, 0.f));
        }
        *(bf16x4*)(myrow + c0) = pk;
    }
    *(bf16x4*)(myrow + 112 + 4 * g) = (bf16x4){0, 0, 0, 0};   // zero cols 112..127

    // ---- phase 3a: acts1 = relu(acts0 @ Wd^T + bd), MFMA, K=128 ----
    f32x4 acc2[7];
    #pragma unroll
    for (int ct = 0; ct < 7; ++ct) acc2[ct] = (f32x4){0.f, 0.f, 0.f, 0.f};
    #pragma unroll
    for (int kk = 0; kk < 4; ++kk) {
        int k0 = kk * 32;
        bf16x8 bfrag = *(const bf16x8*)(myrow + k0 + g * 8);
        #pragma unroll
        for (int ct = 0; ct < 7; ++ct) {
            bf16x8 afrag = *(const bf16x8*)(wd + (16 * ct + r) * 128 + k0 + g * 8);
            acc2[ct] = __builtin_amdgcn_mfma_f32_16x16x32_bf16(afrag, bfrag, acc2[ct], 0, 0, 0);
        }
    }

    float a1r[28];
    #pragma unroll
    for (int ct = 0; ct < 7; ++ct) {
        #pragma unroll
        for (int j = 0; j < 4; ++j) {
            int te = 16 * ct + 4 * g + j;
            float bias = (te < SD) ? ws[BD_F + te] : 0.f;
            a1r[ct * 4 + j] = fmaxf(acc2[ct][j] + bias, 0.f);
        }
    }

    // ---- phase 3b: logits = acts1 @ Wo_eff^T + blog; log_softmax ----
    float part[10];
    #pragma unroll
    for (int o = 0; o < 10; ++o) part[o] = 0.f;
    #pragma unroll
    for (int ct = 0; ct < 7; ++ct) {
        int te0 = 16 * ct + 4 * g;
        #pragma unroll
        for (int o = 0; o < 10; ++o) {
            float4 wv = *(const float4*)(ws + WO_F + o * 112 + te0);
            part[o] += a1r[ct * 4 + 0] * wv.x + a1r[ct * 4 + 1] * wv.y
                     + a1r[ct * 4 + 2] * wv.z + a1r[ct * 4 + 3] * wv.w;
        }
    }
    #pragma unroll
    for (int o = 0; o < 10; ++o) {
        part[o] += __shfl_xor(part[o], 16, 64);
        part[o] += __shfl_xor(part[o], 32, 64);
    }
    if (g == 0) {
        float lg[10];
        float m = -1e30f;
        #pragma unroll
        for (int o = 0; o < 10; ++o) {
            lg[o] = part[o] + ws[BL_F + o];
            m = fmaxf(m, lg[o]);
        }
        float s = 0.f;
        #pragma unroll
        for (int o = 0; o < 10; ++o) s += expf(lg[o] - m);
        float z = m + logf(s);
        float* ob = out + grow * N_OUTS;
        #pragma unroll
        for (int q = 0; q < 5; ++q)
            *(float2*)(ob + 2 * q) = make_float2(lg[2 * q] - z, lg[2 * q + 1] - z);
    }
}

extern "C" void kernel_launch(void* const* d_in, const int* in_sizes, int n_in,
                              void* d_out, int out_size, void* d_ws, size_t ws_size,
                              hipStream_t stream) {
    const float* x      = (const float*)d_in[0];
    const float* W_in   = (const float*)d_in[1];
    const float* b_in   = (const float*)d_in[2];
    const float* W_gate = (const float*)d_in[3];
    const float* b_gate = (const float*)d_in[4];
    const float* W_data = (const float*)d_in[5];
    const float* b_data = (const float*)d_in[6];
    const float* W_out  = (const float*)d_in[7];
    const float* b_out  = (const float*)d_in[8];
    float* out = (float*)d_out;
    float* ws  = (float*)d_ws;

    prep1_kernel<<<1, 256, 0, stream>>>(x, W_in, b_in, W_gate, b_gate,
                                        b_data, W_out, b_out, out, ws);
    prep2_kernel<<<256, 256, 0, stream>>>(W_in, W_data, ws);
    main_kernel<<<BATCH / 64, 256, 0, stream>>>(x, b_in, ws, out);
}

// Round 4
// 121.665 us; speedup vs baseline: 1.0493x; 1.0493x over previous
//
#include <hip/hip_runtime.h>
#include <math.h>

#define BATCH   65536
#define N_IN    784
#define DD      10
#define NB      10
#define SD      100
#define N_OUTS  10

typedef float  f32x4  __attribute__((ext_vector_type(4)));
typedef short  bf16x8 __attribute__((ext_vector_type(8)));
typedef short  bf16x4 __attribute__((ext_vector_type(4)));

// ws float offsets
#define WTF_F 0        // bf16 frag-linear Wt: [25 K][7 ct][64 lane][8]   (44800 f)
#define WDF_F 44800    // bf16 frag-linear Wd: [4 kk][7 ct][64 lane][8]   (7168 f)
#define BD_F  51968    // f32 [100] bd_eff (te order)
#define WO_F  52068    // f32 [10][112] any_open-folded W_out, zero-pad
#define BL_F  53188    // f32 [10] blog
#define MK_F  53198    // f32 [100] mask

__device__ __forceinline__ short f2bf(float f) {
    unsigned u = __builtin_bit_cast(unsigned, f);
    unsigned r = u + 0x7fffu + ((u >> 16) & 1u);   // RNE
    return (short)(r >> 16);
}

__device__ __forceinline__ bf16x8 pack8(float4 lo, float4 hi) {
    bf16x8 v;
    v[0] = f2bf(lo.x); v[1] = f2bf(lo.y); v[2] = f2bf(lo.z); v[3] = f2bf(lo.w);
    v[4] = f2bf(hi.x); v[5] = f2bf(hi.y); v[6] = f2bf(hi.z); v[7] = f2bf(hi.w);
    return v;
}

// ---------------- prep1: exact fp32 gating + small folded tables ----------------
__global__ void prep1_kernel(const float* __restrict__ x,
                             const float* __restrict__ W_in,
                             const float* __restrict__ b_in,
                             const float* __restrict__ W_gate,
                             const float* __restrict__ b_gate,
                             const float* __restrict__ b_data,
                             const float* __restrict__ W_out,
                             const float* __restrict__ b_out,
                             float* __restrict__ out,
                             float* __restrict__ ws) {
    __shared__ float a0r0[SD];
    __shared__ float mask_l[SD];
    __shared__ float ao_l[NB];
    const int tid = threadIdx.x;

    if (tid < SD) {                      // acts0 for batch row 0 (exact fp32)
        int s = tid / DD, d = tid % DD;
        float acc = b_in[tid];
        for (int i = 0; i < N_IN; ++i)
            acc += x[i] * W_in[s * (N_IN * DD) + i * DD + d];
        a0r0[tid] = fmaxf(acc, 0.f);
    }
    __syncthreads();

    if (tid < SD) {                      // gate[s][t] -> mask
        float g = b_gate[tid];
        int s = tid / DD;
        for (int d = 0; d < DD; ++d)
            g += a0r0[s * DD + d] * W_gate[tid * DD + d];
        mask_l[tid] = (g > 0.f) ? 1.f : 0.f;
    }
    __syncthreads();

    if (tid < NB) {
        float any = 0.f;
        for (int s = 0; s < NB; ++s) any = fmaxf(any, mask_l[s * DD + tid]);
        ao_l[tid] = any;
    }
    if (tid == 0) {
        float sum = 0.f;
        for (int i = 0; i < SD; ++i) sum += mask_l[i];
        out[(long)BATCH * N_OUTS] = sum / 20.0f;          // prob_open_gate
    }
    __syncthreads();

    if (tid < SD) ws[MK_F + tid] = mask_l[tid];

    if (tid < SD) {                      // bd_eff
        int t = tid / DD, e = tid % DD;
        float v = 0.f;
        for (int s = 0; s < NB; ++s)
            v += mask_l[s * DD + t] * b_data[(s * NB + t) * DD + e];
        ws[BD_F + tid] = v;
    }
    for (int idx = tid; idx < 10 * 112; idx += blockDim.x) {   // Wo_eff
        int o = idx / 112, te = idx % 112;
        float v = 0.f;
        if (te < SD) {
            int t = te / DD, e = te % DD;
            v = ao_l[t] * W_out[(t * DD + e) * N_OUTS + o];
        }
        ws[WO_F + idx] = v;
    }
    if (tid < N_OUTS) {                  // blog
        float v = 0.f;
        for (int t = 0; t < NB; ++t) v += ao_l[t] * b_out[t * N_OUTS + tid];
        ws[BL_F + tid] = v;
    }
}

// ---------------- prep2: bf16 fragment-linear weight tables ----------------
__global__ void prep2_kernel(const float* __restrict__ W_in,
                             const float* __restrict__ W_data,
                             float* __restrict__ ws) {
    short* wtf = (short*)(ws + WTF_F);
    short* wdf = (short*)(ws + WDF_F);
    const float* mask = ws + MK_F;
    const int n1 = 25 * 7 * 512;     // 89600
    const int n2 = 4 * 7 * 512;      // 14336
    for (int idx = blockIdx.x * blockDim.x + threadIdx.x; idx < n1 + n2;
         idx += gridDim.x * blockDim.x) {
        if (idx < n1) {
            int K = idx / 3584, rem = idx % 3584;
            int ct = rem / 512, l2 = rem % 512;
            int l = l2 >> 3, e = l2 & 7;
            int r = l & 15, g = l >> 4;
            int c = 16 * ct + r, k = K * 32 + g * 8 + e;
            float v = (c < SD && k < N_IN)
                          ? W_in[(c / DD) * (N_IN * DD) + k * DD + (c % DD)] : 0.f;
            wtf[idx] = f2bf(v);
        } else {
            int i2 = idx - n1;
            int kk = i2 / 3584, rem = i2 % 3584;
            int ct = rem / 512, l2 = rem % 512;
            int l = l2 >> 3, e = l2 & 7;
            int r = l & 15, g = l >> 4;
            int m = 16 * ct + r, k = kk * 32 + g * 8 + e;
            float v = 0.f;
            if (m < SD && k < SD) {
                int t = m / DD, eo = m % DD, s = k / DD, d = k % DD;
                v = mask[s * DD + t] * W_data[((s * NB + t) * DD + d) * DD + eo];
            }
            wdf[i2] = f2bf(v);
        }
    }
}

// ---------------- main: async-staged x + k-split MFMA + routed tail ----------------
// LDS: [0,51200) x-tile, 16 rows x 3200B, XOR-swizzled (off ^ ((row&7)<<4)).
//      partial bufs for waves 1-3 alias x-tile after phase2 (3 x 7168B).
//      [51200,55552) a0b bf16 [16][136].
__global__ __launch_bounds__(256) void main_kernel(
        const float* __restrict__ x,
        const float* __restrict__ b_in,
        const float* __restrict__ ws,
        float* __restrict__ out) {
    __shared__ __align__(16) unsigned char lds[55552];

    const int tid  = threadIdx.x;
    const int w    = tid >> 6;
    const int lane = tid & 63;
    const int g    = lane >> 4;
    const int r    = lane & 15;
    const char* xblk = (const char*)x + (size_t)blockIdx.x * 50176;

    // ---- stage x tile: 50 x global_load_lds dwordx4, linear dest, pre-swizzled src ----
    #pragma unroll
    for (int q = 0; q < 13; ++q) {
        int I = w + 4 * q;                       // wave-uniform
        if (I < 50) {
            int D = I * 1024 + lane * 16;        // linear dest byte
            int row = D / 3200;
            int off = D - row * 3200;
            int soff = off ^ ((row & 7) << 4);   // inverse swizzle on source
            if (soff >= 3136) soff = 0;          // pad region: any finite bytes (x *0 later)
            __builtin_amdgcn_global_load_lds(
                (const __attribute__((address_space(1))) unsigned int*)(xblk + row * 3136 + soff),
                (__attribute__((address_space(3))) unsigned int*)(lds + I * 1024),
                16, 0, 0);
        }
    }
    __syncthreads();

    // ---- phase 2: k-split MFMA; wave w does k-steps {w, w+4, ...} of 25 ----
    f32x4 acc[7];
    #pragma unroll
    for (int ct = 0; ct < 7; ++ct) acc[ct] = (f32x4){0.f, 0.f, 0.f, 0.f};

    const short* wtf = (const short*)(ws + WTF_F);
    const int sw = (r & 7) << 4;
    for (int K = w; K < 25; K += 4) {
        int cb = K * 128 + g * 32;
        float4 lo = *(const float4*)(lds + r * 3200 + (cb ^ sw));
        float4 hi = *(const float4*)(lds + r * 3200 + ((cb + 16) ^ sw));
        bf16x8 bfrag = pack8(lo, hi);
        const short* wk = wtf + K * 3584 + lane * 8;
        #pragma unroll
        for (int ct = 0; ct < 7; ++ct) {
            bf16x8 afrag = *(const bf16x8*)(wk + ct * 512);
            acc[ct] = __builtin_amdgcn_mfma_f32_16x16x32_bf16(afrag, bfrag, acc[ct], 0, 0, 0);
        }
    }
    __syncthreads();                             // all xs reads done

    // ---- waves 1-3: dump partials (alias dead x-tile) ----
    if (w > 0) {
        float* buf = (float*)(lds + (w - 1) * 7168);
        #pragma unroll
        for (int ct = 0; ct < 7; ++ct)
            *(f32x4*)(buf + r * 112 + 16 * ct + 4 * g) = acc[ct];
    }
    __syncthreads();

    if (w == 0) {
        // ---- reduce + bias + relu -> a0b bf16 [16][136] ----
        short* a0b = (short*)(lds + 51200);
        short* myrow = a0b + r * 136;
        const float* bufs = (const float*)lds;
        #pragma unroll
        for (int ct = 0; ct < 7; ++ct) {
            int c0 = 16 * ct + 4 * g;
            int o = r * 112 + c0;
            f32x4 p0 = *(const f32x4*)(bufs + o);
            f32x4 p1 = *(const f32x4*)(bufs + 1792 + o);
            f32x4 p2 = *(const f32x4*)(bufs + 3584 + o);
            bf16x4 pk;
            #pragma unroll
            for (int j = 0; j < 4; ++j) {
                int c = c0 + j;
                float bias = (c < SD) ? b_in[c] : 0.f;
                float v = acc[ct][j] + p0[j] + p1[j] + p2[j] + bias;
                pk[j] = f2bf(fmaxf(v, 0.f));
            }
            *(bf16x4*)(myrow + c0) = pk;
        }
        *(bf16x4*)(myrow + 112 + 4 * g) = (bf16x4){0, 0, 0, 0};   // cols 112..127

        // ---- phase 3a: acts1 = relu(acts0 @ Wd^T + bd), MFMA K=128 ----
        const short* wdf = (const short*)(ws + WDF_F);
        f32x4 acc2[7];
        #pragma unroll
        for (int ct = 0; ct < 7; ++ct) acc2[ct] = (f32x4){0.f, 0.f, 0.f, 0.f};
        #pragma unroll
        for (int kk = 0; kk < 4; ++kk) {
            bf16x8 bfrag = *(const bf16x8*)(myrow + kk * 32 + g * 8);
            #pragma unroll
            for (int ct = 0; ct < 7; ++ct) {
                bf16x8 afrag = *(const bf16x8*)(wdf + kk * 3584 + ct * 512 + lane * 8);
                acc2[ct] = __builtin_amdgcn_mfma_f32_16x16x32_bf16(afrag, bfrag, acc2[ct], 0, 0, 0);
            }
        }
        float a1r[28];
        #pragma unroll
        for (int ct = 0; ct < 7; ++ct) {
            #pragma unroll
            for (int j = 0; j < 4; ++j) {
                int te = 16 * ct + 4 * g + j;
                float bias = (te < SD) ? ws[BD_F + te] : 0.f;
                a1r[ct * 4 + j] = fmaxf(acc2[ct][j] + bias, 0.f);
            }
        }

        // ---- phase 3b: logits + log_softmax ----
        float part[10];
        #pragma unroll
        for (int o = 0; o < 10; ++o) part[o] = 0.f;
        #pragma unroll
        for (int ct = 0; ct < 7; ++ct) {
            int te0 = 16 * ct + 4 * g;
            #pragma unroll
            for (int o = 0; o < 10; ++o) {
                float4 wv = *(const float4*)(ws + WO_F + o * 112 + te0);
                part[o] += a1r[ct * 4 + 0] * wv.x + a1r[ct * 4 + 1] * wv.y
                         + a1r[ct * 4 + 2] * wv.z + a1r[ct * 4 + 3] * wv.w;
            }
        }
        #pragma unroll
        for (int o = 0; o < 10; ++o) {
            part[o] += __shfl_xor(part[o], 16, 64);
            part[o] += __shfl_xor(part[o], 32, 64);
        }
        if (g == 0) {
            float lg[10];
            float m = -1e30f;
            #pragma unroll
            for (int o = 0; o < 10; ++o) {
                lg[o] = part[o] + ws[BL_F + o];
                m = fmaxf(m, lg[o]);
            }
            float s = 0.f;
            #pragma unroll
            for (int o = 0; o < 10; ++o) s += expf(lg[o] - m);
            float z = m + logf(s);
            float* ob = out + ((size_t)blockIdx.x * 16 + r) * N_OUTS;
            #pragma unroll
            for (int q2 = 0; q2 < 5; ++q2)
                *(float2*)(ob + 2 * q2) = make_float2(lg[2 * q2] - z, lg[2 * q2 + 1] - z);
        }
    }
}

extern "C" void kernel_launch(void* const* d_in, const int* in_sizes, int n_in,
                              void* d_out, int out_size, void* d_ws, size_t ws_size,
                              hipStream_t stream) {
    const float* x      = (const float*)d_in[0];
    const float* W_in   = (const float*)d_in[1];
    const float* b_in   = (const float*)d_in[2];
    const float* W_gate = (const float*)d_in[3];
    const float* b_gate = (const float*)d_in[4];
    const float* W_data = (const float*)d_in[5];
    const float* b_data = (const float*)d_in[6];
    const float* W_out  = (const float*)d_in[7];
    const float* b_out  = (const float*)d_in[8];
    float* out = (float*)d_out;
    float* ws  = (float*)d_ws;

    prep1_kernel<<<1, 256, 0, stream>>>(x, W_in, b_in, W_gate, b_gate,
                                        b_data, W_out, b_out, out, ws);
    prep2_kernel<<<256, 256, 0, stream>>>(W_in, W_data, ws);
    main_kernel<<<BATCH / 16, 256, 0, stream>>>(x, b_in, ws, out);
}

// Round 5
// 119.524 us; speedup vs baseline: 1.0681x; 1.0179x over previous
//
#include <hip/hip_runtime.h>
#include <math.h>

#define BATCH   65536
#define N_IN    784
#define DD      10
#define NB      10
#define SD      100
#define N_OUTS  10
#define TILES   16
#define ROWSPT  16

typedef float  f32x4  __attribute__((ext_vector_type(4)));
typedef short  bf16x8 __attribute__((ext_vector_type(8)));

// ws float offsets
#define WTF_F 0        // bf16 [25 K][8 ct][512]  frag-linear padded Wt
#define WDF_F 51200    // bf16 [4 kk][8 ct][512]  frag-linear padded Wd_eff
#define BD_F  59392    // f32 [128] bd_eff zero-padded
#define WO_F  59520    // f32 [10][112] Wo_eff
#define BL_F  60640    // f32 [10] blog
#define MK_F  60650    // f32 [100] mask

__device__ __forceinline__ short f2bf(float f) {
    unsigned u = __builtin_bit_cast(unsigned, f);
    unsigned r = u + 0x7fffu + ((u >> 16) & 1u);   // RNE
    return (short)(r >> 16);
}

__device__ __forceinline__ bf16x8 pack8cvt(float4 lo, float4 hi) {
    union { unsigned u[4]; bf16x8 v; } o;
    asm("v_cvt_pk_bf16_f32 %0, %1, %2" : "=v"(o.u[0]) : "v"(lo.x), "v"(lo.y));
    asm("v_cvt_pk_bf16_f32 %0, %1, %2" : "=v"(o.u[1]) : "v"(lo.z), "v"(lo.w));
    asm("v_cvt_pk_bf16_f32 %0, %1, %2" : "=v"(o.u[2]) : "v"(hi.x), "v"(hi.y));
    asm("v_cvt_pk_bf16_f32 %0, %1, %2" : "=v"(o.u[3]) : "v"(hi.z), "v"(hi.w));
    return o.v;
}

#define BAR_LGKM() do { asm volatile("s_waitcnt lgkmcnt(0)" ::: "memory"); \
    __builtin_amdgcn_s_barrier(); __builtin_amdgcn_sched_barrier(0); } while (0)

// ---------------- prep1: exact fp32 gating + small folded tables ----------------
__global__ void prep1_kernel(const float* __restrict__ x,
                             const float* __restrict__ W_in,
                             const float* __restrict__ b_in,
                             const float* __restrict__ W_gate,
                             const float* __restrict__ b_gate,
                             const float* __restrict__ b_data,
                             const float* __restrict__ W_out,
                             const float* __restrict__ b_out,
                             float* __restrict__ out,
                             float* __restrict__ ws) {
    __shared__ float a0r0[SD];
    __shared__ float mask_l[SD];
    __shared__ float ao_l[NB];
    const int tid = threadIdx.x;

    if (tid < SD) {                      // acts0 for batch row 0 (exact fp32)
        int s = tid / DD, d = tid % DD;
        float acc = b_in[tid];
        for (int i = 0; i < N_IN; ++i)
            acc += x[i] * W_in[s * (N_IN * DD) + i * DD + d];
        a0r0[tid] = fmaxf(acc, 0.f);
    }
    __syncthreads();

    if (tid < SD) {                      // gate[s][t] -> mask
        float g = b_gate[tid];
        int s = tid / DD;
        for (int d = 0; d < DD; ++d)
            g += a0r0[s * DD + d] * W_gate[tid * DD + d];
        mask_l[tid] = (g > 0.f) ? 1.f : 0.f;
    }
    __syncthreads();

    if (tid < NB) {
        float any = 0.f;
        for (int s = 0; s < NB; ++s) any = fmaxf(any, mask_l[s * DD + tid]);
        ao_l[tid] = any;
    }
    if (tid == 0) {
        float sum = 0.f;
        for (int i = 0; i < SD; ++i) sum += mask_l[i];
        out[(long)BATCH * N_OUTS] = sum / 20.0f;          // prob_open_gate
    }
    __syncthreads();

    if (tid < SD) ws[MK_F + tid] = mask_l[tid];

    for (int idx = tid; idx < 128; idx += blockDim.x) {    // bd_eff padded
        float v = 0.f;
        if (idx < SD) {
            int t = idx / DD, e = idx % DD;
            for (int s = 0; s < NB; ++s)
                v += mask_l[s * DD + t] * b_data[(s * NB + t) * DD + e];
        }
        ws[BD_F + idx] = v;
    }
    for (int idx = tid; idx < 10 * 112; idx += blockDim.x) {   // Wo_eff
        int o = idx / 112, te = idx % 112;
        float v = 0.f;
        if (te < SD) {
            int t = te / DD, e = te % DD;
            v = ao_l[t] * W_out[(t * DD + e) * N_OUTS + o];
        }
        ws[WO_F + idx] = v;
    }
    if (tid < N_OUTS) {                  // blog
        float v = 0.f;
        for (int t = 0; t < NB; ++t) v += ao_l[t] * b_out[t * N_OUTS + tid];
        ws[BL_F + tid] = v;
    }
}

// ---------------- prep2: bf16 fragment-linear weight tables (8-ct padded) ----------------
__global__ void prep2_kernel(const float* __restrict__ W_in,
                             const float* __restrict__ W_data,
                             float* __restrict__ ws) {
    short* wtf = (short*)(ws + WTF_F);
    short* wdf = (short*)(ws + WDF_F);
    const float* mask = ws + MK_F;
    const int n1 = 25 * 8 * 512;     // 102400
    const int n2 = 4 * 8 * 512;      // 16384
    for (int idx = blockIdx.x * blockDim.x + threadIdx.x; idx < n1 + n2;
         idx += gridDim.x * blockDim.x) {
        if (idx < n1) {
            int K = idx / 4096, rem = idx % 4096;
            int ct = rem / 512, l2 = rem % 512;
            int l = l2 >> 3, e = l2 & 7;
            int r = l & 15, g = l >> 4;
            int c = 16 * ct + r, k = K * 32 + g * 8 + e;
            float v = (c < SD && k < N_IN)
                          ? W_in[(c / DD) * (N_IN * DD) + k * DD + (c % DD)] : 0.f;
            wtf[idx] = f2bf(v);
        } else {
            int i2 = idx - n1;
            int kk = i2 / 4096, rem = i2 % 4096;
            int ct = rem / 512, l2 = rem % 512;
            int l = l2 >> 3, e = l2 & 7;
            int r = l & 15, g = l >> 4;
            int m = 16 * ct + r, k = kk * 32 + g * 8 + e;
            float v = 0.f;
            if (m < SD && k < SD) {
                int t = m / DD, eo = m % DD, s = k / DD, d = k % DD;
                v = mask[s * DD + t] * W_data[((s * NB + t) * DD + d) * DD + eo];
            }
            wdf[i2] = f2bf(v);
        }
    }
}

// ---------------- main: persistent blocks, double-buffered DMA, reg-resident weights ----------------
// LDS: xbuf0 @0 (51200), xbuf1 @51200 (51200), a0b bf16[16][128] @102400 (4096),
//      a1 f32[16][128] @106496 (8192), Wo f32[10][112] @114688 (4480),
//      bl @119168 (64), logits f32[16][10] @119232 (640)  => 119872 B
__global__ __launch_bounds__(512, 2) void main_kernel(
        const float* __restrict__ x,
        const float* __restrict__ b_in,
        const float* __restrict__ ws,
        float* __restrict__ out) {
    __shared__ __align__(16) unsigned char lds[119872];
    unsigned char* a0b = lds + 102400;
    float* a1  = (float*)(lds + 106496);
    float* WoL = (float*)(lds + 114688);
    float* blL = (float*)(lds + 119168);
    float* lgL = (float*)(lds + 119232);

    const int tid  = threadIdx.x;
    const int w    = tid >> 6;
    const int lane = tid & 63;
    const int g    = lane >> 4;
    const int r    = lane & 15;
    const size_t rowbase = (size_t)blockIdx.x * (TILES * ROWSPT);

    const short* wtf = (const short*)(ws + WTF_F);
    const short* wdf = (const short*)(ws + WDF_F);

    // ---- one-time: weights -> registers; Wo/bl -> LDS; biases -> registers ----
    bf16x8 wtreg[25];
    #pragma unroll
    for (int K = 0; K < 25; ++K)
        wtreg[K] = *(const bf16x8*)(wtf + (K * 8 + w) * 512 + lane * 8);
    bf16x8 wdreg[4];
    #pragma unroll
    for (int kk = 0; kk < 4; ++kk)
        wdreg[kk] = *(const bf16x8*)(wdf + (kk * 8 + w) * 512 + lane * 8);

    float binv[4], bdv[4];
    #pragma unroll
    for (int j = 0; j < 4; ++j) {
        int c = 16 * w + 4 * g + j;
        binv[j] = (c < SD) ? b_in[c] : 0.f;
        bdv[j]  = ws[BD_F + c];
    }
    for (int idx = tid; idx < 1120; idx += 512) WoL[idx] = ws[WO_F + idx];
    if (tid < 10) blL[tid] = ws[BL_F + tid];

    // ---- async stage of one 16-row tile (50 KB) into buf ----
    auto STAGE = [&](int tile, int buf) {
        const char* src = (const char*)(x + (rowbase + (size_t)tile * ROWSPT) * N_IN);
        #pragma unroll
        for (int q = 0; q < 7; ++q) {
            int I = w + 8 * q;
            if (I < 50) {
                int D = I * 1024 + lane * 16;
                int row = D / 3200;
                int off = D - row * 3200;
                int soff = off ^ ((row & 7) << 4);
                if (soff >= 3136) soff = 0;     // pad image: any finite bytes
                __builtin_amdgcn_global_load_lds(
                    (const __attribute__((address_space(1))) unsigned int*)(src + row * 3136 + soff),
                    (__attribute__((address_space(3))) unsigned int*)(lds + buf * 51200 + I * 1024 + lane * 16),
                    16, 0, 0);
            }
        }
    };

    STAGE(0, 0);

    for (int t = 0; t < TILES; ++t) {
        const int cur = t & 1;
        __syncthreads();                 // B1: drains vmcnt -> buf[cur] ready
        if (t + 1 < TILES) STAGE(t + 1, cur ^ 1);   // in flight across B2-B4

        // ---- phase 2: acts0 cols [16w,16w+16) over all K ----
        f32x4 accA = (f32x4){0.f, 0.f, 0.f, 0.f};
        f32x4 accB = (f32x4){0.f, 0.f, 0.f, 0.f};
        const unsigned char* xb = lds + cur * 51200 + r * 3200;
        const int sw = (r & 7) << 4;
        #pragma unroll
        for (int K = 0; K < 25; ++K) {
            int cb = K * 128 + g * 32;
            float4 lo = *(const float4*)(xb + (cb ^ sw));
            float4 hi = *(const float4*)(xb + ((cb + 16) ^ sw));
            bf16x8 bfrag = pack8cvt(lo, hi);
            if (K & 1)
                accB = __builtin_amdgcn_mfma_f32_16x16x32_bf16(wtreg[K], bfrag, accB, 0, 0, 0);
            else
                accA = __builtin_amdgcn_mfma_f32_16x16x32_bf16(wtreg[K], bfrag, accA, 0, 0, 0);
        }
        {
            float v0 = fmaxf(accA[0] + accB[0] + binv[0], 0.f);
            float v1 = fmaxf(accA[1] + accB[1] + binv[1], 0.f);
            float v2 = fmaxf(accA[2] + accB[2] + binv[2], 0.f);
            float v3 = fmaxf(accA[3] + accB[3] + binv[3], 0.f);
            unsigned p01, p23;
            asm("v_cvt_pk_bf16_f32 %0, %1, %2" : "=v"(p01) : "v"(v0), "v"(v1));
            asm("v_cvt_pk_bf16_f32 %0, %1, %2" : "=v"(p23) : "v"(v2), "v"(v3));
            *(uint2*)(a0b + r * 256 + (16 * w + 4 * g) * 2) = make_uint2(p01, p23);
        }
        BAR_LGKM();                      // B2 (vmcnt NOT drained)

        // ---- phase 3a: acts1 cols [16w,16w+16), K=128 from a0b ----
        f32x4 acc2 = (f32x4){0.f, 0.f, 0.f, 0.f};
        #pragma unroll
        for (int kk = 0; kk < 4; ++kk) {
            bf16x8 bfrag = *(const bf16x8*)(a0b + r * 256 + (kk * 32 + g * 8) * 2);
            acc2 = __builtin_amdgcn_mfma_f32_16x16x32_bf16(wdreg[kk], bfrag, acc2, 0, 0, 0);
        }
        {
            f32x4 av;
            #pragma unroll
            for (int j = 0; j < 4; ++j) av[j] = fmaxf(acc2[j] + bdv[j], 0.f);
            *(f32x4*)(a1 + r * 128 + 16 * w + 4 * g) = av;
        }
        BAR_LGKM();                      // B3

        // ---- phase 3b: logits ----
        if (tid < 160) {
            int rr = tid / 10, o = tid - rr * 10;
            float s = blL[o];
            const f32x4* av = (const f32x4*)(a1 + rr * 128);
            const float* wo = WoL + o * 112;
            #pragma unroll
            for (int q2 = 0; q2 < 28; ++q2) {
                f32x4 a = av[q2];
                f32x4 wv = *(const f32x4*)(wo + q2 * 4);
                s += a[0] * wv[0] + a[1] * wv[1] + a[2] * wv[2] + a[3] * wv[3];
            }
            lgL[tid] = s;
        }
        BAR_LGKM();                      // B4

        // ---- softmax + store ----
        if (tid < 160) {
            int rr = tid / 10, o = tid - rr * 10;
            float m = -1e30f;
            #pragma unroll
            for (int j = 0; j < 10; ++j) m = fmaxf(m, lgL[rr * 10 + j]);
            float ssum = 0.f;
            #pragma unroll
            for (int j = 0; j < 10; ++j) ssum += expf(lgL[rr * 10 + j] - m);
            out[(rowbase + (size_t)t * ROWSPT + rr) * N_OUTS + o] =
                lgL[tid] - m - logf(ssum);
        }
    }
}

extern "C" void kernel_launch(void* const* d_in, const int* in_sizes, int n_in,
                              void* d_out, int out_size, void* d_ws, size_t ws_size,
                              hipStream_t stream) {
    const float* x      = (const float*)d_in[0];
    const float* W_in   = (const float*)d_in[1];
    const float* b_in   = (const float*)d_in[2];
    const float* W_gate = (const float*)d_in[3];
    const float* b_gate = (const float*)d_in[4];
    const float* W_data = (const float*)d_in[5];
    const float* b_data = (const float*)d_in[6];
    const float* W_out  = (const float*)d_in[7];
    const float* b_out  = (const float*)d_in[8];
    float* out = (float*)d_out;
    float* ws  = (float*)d_ws;

    prep1_kernel<<<1, 256, 0, stream>>>(x, W_in, b_in, W_gate, b_gate,
                                        b_data, W_out, b_out, out, ws);
    prep2_kernel<<<256, 256, 0, stream>>>(W_in, W_data, ws);
    main_kernel<<<256, 512, 0, stream>>>(x, b_in, ws, out);
}

// Round 7
// 112.722 us; speedup vs baseline: 1.1326x; 1.0603x over previous
//
#include <hip/hip_runtime.h>
#include <math.h>

#define BATCH   65536
#define N_IN    784
#define DD      10
#define NB      10
#define SD      100
#define N_OUTS  10

typedef float  f32x4  __attribute__((ext_vector_type(4)));
typedef short  bf16x8 __attribute__((ext_vector_type(8)));

// ws float offsets (same layout as R5)
#define WTF_F 0        // bf16 [25 K][8 ct][512]  frag-linear padded Wt
#define WDF_F 51200    // bf16 [4 kk][8 ct][512]  frag-linear padded Wd_eff
#define BD_F  59392    // f32 [128] bd_eff zero-padded
#define WO_F  59520    // f32 [10][112] Wo_eff
#define BL_F  60640    // f32 [10] blog
#define MK_F  60650    // f32 [100] mask

__device__ __forceinline__ short f2bf(float f) {
    unsigned u = __builtin_bit_cast(unsigned, f);
    unsigned r = u + 0x7fffu + ((u >> 16) & 1u);   // RNE
    return (short)(r >> 16);
}

// ---------------- prep1: exact fp32 gating + small folded tables ----------------
__global__ void prep1_kernel(const float* __restrict__ x,
                             const float* __restrict__ W_in,
                             const float* __restrict__ b_in,
                             const float* __restrict__ W_gate,
                             const float* __restrict__ b_gate,
                             const float* __restrict__ b_data,
                             const float* __restrict__ W_out,
                             const float* __restrict__ b_out,
                             float* __restrict__ out,
                             float* __restrict__ ws) {
    __shared__ float a0r0[SD];
    __shared__ float mask_l[SD];
    __shared__ float ao_l[NB];
    const int tid = threadIdx.x;

    if (tid < SD) {                      // acts0 for batch row 0 (exact fp32)
        int s = tid / DD, d = tid % DD;
        float acc = b_in[tid];
        for (int i = 0; i < N_IN; ++i)
            acc += x[i] * W_in[s * (N_IN * DD) + i * DD + d];
        a0r0[tid] = fmaxf(acc, 0.f);
    }
    __syncthreads();

    if (tid < SD) {                      // gate[s][t] -> mask
        float g = b_gate[tid];
        int s = tid / DD;
        for (int d = 0; d < DD; ++d)
            g += a0r0[s * DD + d] * W_gate[tid * DD + d];
        mask_l[tid] = (g > 0.f) ? 1.f : 0.f;
    }
    __syncthreads();

    if (tid < NB) {
        float any = 0.f;
        for (int s = 0; s < NB; ++s) any = fmaxf(any, mask_l[s * DD + tid]);
        ao_l[tid] = any;
    }
    if (tid == 0) {
        float sum = 0.f;
        for (int i = 0; i < SD; ++i) sum += mask_l[i];
        out[(long)BATCH * N_OUTS] = sum / 20.0f;          // prob_open_gate
    }
    __syncthreads();

    if (tid < SD) ws[MK_F + tid] = mask_l[tid];

    for (int idx = tid; idx < 128; idx += blockDim.x) {    // bd_eff padded
        float v = 0.f;
        if (idx < SD) {
            int t = idx / DD, e = idx % DD;
            for (int s = 0; s < NB; ++s)
                v += mask_l[s * DD + t] * b_data[(s * NB + t) * DD + e];
        }
        ws[BD_F + idx] = v;
    }
    for (int idx = tid; idx < 10 * 112; idx += blockDim.x) {   // Wo_eff
        int o = idx / 112, te = idx % 112;
        float v = 0.f;
        if (te < SD) {
            int t = te / DD, e = te % DD;
            v = ao_l[t] * W_out[(t * DD + e) * N_OUTS + o];
        }
        ws[WO_F + idx] = v;
    }
    if (tid < N_OUTS) {                  // blog
        float v = 0.f;
        for (int t = 0; t < NB; ++t) v += ao_l[t] * b_out[t * N_OUTS + tid];
        ws[BL_F + tid] = v;
    }
}

// ---------------- prep2: bf16 fragment-linear weight tables (8-ct padded) ----------------
__global__ void prep2_kernel(const float* __restrict__ W_in,
                             const float* __restrict__ W_data,
                             float* __restrict__ ws) {
    short* wtf = (short*)(ws + WTF_F);
    short* wdf = (short*)(ws + WDF_F);
    const float* mask = ws + MK_F;
    const int n1 = 25 * 8 * 512;     // 102400
    const int n2 = 4 * 8 * 512;      // 16384
    for (int idx = blockIdx.x * blockDim.x + threadIdx.x; idx < n1 + n2;
         idx += gridDim.x * blockDim.x) {
        if (idx < n1) {
            int K = idx / 4096, rem = idx % 4096;
            int ct = rem / 512, l2 = rem % 512;
            int l = l2 >> 3, e = l2 & 7;
            int r = l & 15, g = l >> 4;
            int c = 16 * ct + r, k = K * 32 + g * 8 + e;
            float v = (c < SD && k < N_IN)
                          ? W_in[(c / DD) * (N_IN * DD) + k * DD + (c % DD)] : 0.f;
            wtf[idx] = f2bf(v);
        } else {
            int i2 = idx - n1;
            int kk = i2 / 4096, rem = i2 % 4096;
            int ct = rem / 512, l2 = rem % 512;
            int l = l2 >> 3, e = l2 & 7;
            int r = l & 15, g = l >> 4;
            int m = 16 * ct + r, k = kk * 32 + g * 8 + e;
            float v = 0.f;
            if (m < SD && k < SD) {
                int t = m / DD, eo = m % DD, s = k / DD, d = k % DD;
                v = mask[s * DD + t] * W_data[((s * NB + t) * DD + d) * DD + eo];
            }
            wdf[i2] = f2bf(v);
        }
    }
}

// ---- asm-pipelined phase 2 helpers (no tied asm operands) ----
#define ISSUE_X(S, J) do {                                                     \
    const float* _pl;                                                          \
    if ((J) == 24 && g >= 2) _pl = xrow;  /* clamp: zero weights kill it */    \
    else                     _pl = xrow + (J) * 32 + g * 8;                    \
    asm volatile("global_load_dwordx4 %0, %1, off nt"                          \
                 : "=v"(xs[S][0]) : "v"(_pl) : "memory");                      \
    asm volatile("global_load_dwordx4 %0, %1, off nt"                          \
                 : "=v"(xs[S][1]) : "v"(_pl + 4) : "memory");                  \
} while (0)

#define ISSUE_AF(S, J) do {                                                    \
    _Pragma("unroll")                                                          \
    for (int ct = 0; ct < 7; ++ct) {                                           \
        const short* _pa = wtl + ((J) * 8 + ct) * 512;                         \
        asm volatile("global_load_dwordx4 %0, %1, off"                         \
                     : "=v"(afs[S][ct]) : "v"(_pa) : "memory");                \
    }                                                                          \
} while (0)

#define WAITV(CNT) do {                                                        \
    asm volatile("s_waitcnt vmcnt(" #CNT ")" ::: "memory");                    \
    __builtin_amdgcn_sched_barrier(0);                                         \
} while (0)

#define CONSUME(S) do {                                                        \
    union { unsigned u[4]; bf16x8 v; } _o;                                     \
    asm volatile("v_cvt_pk_bf16_f32 %0, %1, %2"                                \
                 : "=v"(_o.u[0]) : "v"(xs[S][0].x), "v"(xs[S][0].y));          \
    asm volatile("v_cvt_pk_bf16_f32 %0, %1, %2"                                \
                 : "=v"(_o.u[1]) : "v"(xs[S][0].z), "v"(xs[S][0].w));          \
    asm volatile("v_cvt_pk_bf16_f32 %0, %1, %2"                                \
                 : "=v"(_o.u[2]) : "v"(xs[S][1].x), "v"(xs[S][1].y));          \
    asm volatile("v_cvt_pk_bf16_f32 %0, %1, %2"                                \
                 : "=v"(_o.u[3]) : "v"(xs[S][1].z), "v"(xs[S][1].w));          \
    _Pragma("unroll")                                                          \
    for (int ct = 0; ct < 7; ++ct)                                             \
        acc[ct] = __builtin_amdgcn_mfma_f32_16x16x32_bf16(afs[S][ct], _o.v,    \
                                                          acc[ct], 0, 0, 0);  \
} while (0)

// ---------------- main: per-wave asm pipeline, NT x loads, no barriers ----------------
__global__ __launch_bounds__(256, 3) void main_kernel(
        const float* __restrict__ x,
        const float* __restrict__ b_in,
        const float* __restrict__ ws,
        float* __restrict__ out) {
    __shared__ __align__(16) short a0b[64 * 136];   // [64 rows][136 bf16], stride 272 B

    const int tid  = threadIdx.x;
    const int w    = tid >> 6;
    const int lane = tid & 63;
    const int g    = lane >> 4;
    const int r    = lane & 15;
    const int lrow = w * 16 + r;
    const long grow = (long)blockIdx.x * 64 + lrow;

    const short* wtf = (const short*)(ws + WTF_F);
    const short* wdf = (const short*)(ws + WDF_F);
    const short* wtl = wtf + lane * 8;
    const float* xrow = x + grow * N_IN;

    f32x4 acc[7];
    #pragma unroll
    for (int ct = 0; ct < 7; ++ct) acc[ct] = (f32x4){0.f, 0.f, 0.f, 0.f};

    float4 xs[2][2];
    bf16x8 afs[2][7];

    // prologue: steps 0 and 1 in flight (9 + 9 loads)
    ISSUE_X(0, 0); ISSUE_AF(0, 0);
    ISSUE_X(1, 1); ISSUE_AF(1, 1);

    #pragma unroll
    for (int j = 0; j < 23; ++j) {
        const int S = j & 1;
        WAITV(9);               // step j's 9 loads done; step j+1's 9 in flight
        CONSUME(S);
        ISSUE_X(S, j + 2);      // refill slot with step j+2
        ISSUE_AF(S, j + 2);
    }
    WAITV(9);  CONSUME(1);      // step 23
    WAITV(0);  CONSUME(0);      // step 24 (full drain)

    // bias + relu + cvt -> a0b row (bf16), cols 112..127 zeroed
    short* myrow = a0b + lrow * 136;
    #pragma unroll
    for (int ct = 0; ct < 7; ++ct) {
        int c0 = 16 * ct + 4 * g;
        float v0 = fmaxf(acc[ct][0] + ((c0 + 0 < SD) ? b_in[c0 + 0] : 0.f), 0.f);
        float v1 = fmaxf(acc[ct][1] + ((c0 + 1 < SD) ? b_in[c0 + 1] : 0.f), 0.f);
        float v2 = fmaxf(acc[ct][2] + ((c0 + 2 < SD) ? b_in[c0 + 2] : 0.f), 0.f);
        float v3 = fmaxf(acc[ct][3] + ((c0 + 3 < SD) ? b_in[c0 + 3] : 0.f), 0.f);
        unsigned p01, p23;
        asm("v_cvt_pk_bf16_f32 %0, %1, %2" : "=v"(p01) : "v"(v0), "v"(v1));
        asm("v_cvt_pk_bf16_f32 %0, %1, %2" : "=v"(p23) : "v"(v2), "v"(v3));
        *(uint2*)(myrow + c0) = make_uint2(p01, p23);
    }
    *(uint2*)(myrow + 112 + 4 * g) = make_uint2(0u, 0u);

    // ---- phase 3a: acts1 = relu(acts0 @ Wd^T + bd), MFMA K=128 (own rows, no barrier) ----
    f32x4 acc2[7];
    #pragma unroll
    for (int ct = 0; ct < 7; ++ct) acc2[ct] = (f32x4){0.f, 0.f, 0.f, 0.f};
    #pragma unroll
    for (int kk = 0; kk < 4; ++kk) {
        bf16x8 bfrag = *(const bf16x8*)(myrow + kk * 32 + g * 8);
        #pragma unroll
        for (int ct = 0; ct < 7; ++ct) {
            bf16x8 afrag = *(const bf16x8*)(wdf + (kk * 8 + ct) * 512 + lane * 8);
            acc2[ct] = __builtin_amdgcn_mfma_f32_16x16x32_bf16(afrag, bfrag, acc2[ct], 0, 0, 0);
        }
    }
    float a1r[28];
    #pragma unroll
    for (int ct = 0; ct < 7; ++ct) {
        #pragma unroll
        for (int j = 0; j < 4; ++j) {
            int te = 16 * ct + 4 * g + j;
            float bias = (te < SD) ? ws[BD_F + te] : 0.f;
            a1r[ct * 4 + j] = fmaxf(acc2[ct][j] + bias, 0.f);
        }
    }

    // ---- phase 3b: logits = acts1 @ Wo_eff^T + blog; shfl-reduce; log_softmax ----
    float part[10];
    #pragma unroll
    for (int o = 0; o < 10; ++o) part[o] = 0.f;
    #pragma unroll
    for (int ct = 0; ct < 7; ++ct) {
        int te0 = 16 * ct + 4 * g;
        #pragma unroll
        for (int o = 0; o < 10; ++o) {
            float4 wv = *(const float4*)(ws + WO_F + o * 112 + te0);
            part[o] += a1r[ct * 4 + 0] * wv.x + a1r[ct * 4 + 1] * wv.y
                     + a1r[ct * 4 + 2] * wv.z + a1r[ct * 4 + 3] * wv.w;
        }
    }
    #pragma unroll
    for (int o = 0; o < 10; ++o) {
        part[o] += __shfl_xor(part[o], 16, 64);
        part[o] += __shfl_xor(part[o], 32, 64);
    }
    if (g == 0) {
        float lg[10];
        float m = -1e30f;
        #pragma unroll
        for (int o = 0; o < 10; ++o) {
            lg[o] = part[o] + ws[BL_F + o];
            m = fmaxf(m, lg[o]);
        }
        float s = 0.f;
        #pragma unroll
        for (int o = 0; o < 10; ++o) s += expf(lg[o] - m);
        float z = m + logf(s);
        float* ob = out + grow * N_OUTS;
        #pragma unroll
        for (int q = 0; q < 5; ++q)
            *(float2*)(ob + 2 * q) = make_float2(lg[2 * q] - z, lg[2 * q + 1] - z);
    }
}

extern "C" void kernel_launch(void* const* d_in, const int* in_sizes, int n_in,
                              void* d_out, int out_size, void* d_ws, size_t ws_size,
                              hipStream_t stream) {
    const float* x      = (const float*)d_in[0];
    const float* W_in   = (const float*)d_in[1];
    const float* b_in   = (const float*)d_in[2];
    const float* W_gate = (const float*)d_in[3];
    const float* b_gate = (const float*)d_in[4];
    const float* W_data = (const float*)d_in[5];
    const float* b_data = (const float*)d_in[6];
    const float* W_out  = (const float*)d_in[7];
    const float* b_out  = (const float*)d_in[8];
    float* out = (float*)d_out;
    float* ws  = (float*)d_ws;

    prep1_kernel<<<1, 256, 0, stream>>>(x, W_in, b_in, W_gate, b_gate,
                                        b_data, W_out, b_out, out, ws);
    prep2_kernel<<<256, 256, 0, stream>>>(W_in, W_data, ws);
    main_kernel<<<BATCH / 64, 256, 0, stream>>>(x, b_in, ws, out);
}

// Round 8
// 103.181 us; speedup vs baseline: 1.2373x; 1.0925x over previous
//
#include <hip/hip_runtime.h>
#include <math.h>

#define BATCH   65536
#define N_IN    784
#define DD      10
#define NB      10
#define SD      100
#define N_OUTS  10

typedef float  f32x4  __attribute__((ext_vector_type(4)));
typedef short  bf16x8 __attribute__((ext_vector_type(8)));

// ws float offsets
#define WTF_F 0        // bf16 [25 K][8 ct][512]  frag-linear padded Wt
#define WDF_F 51200    // bf16 [4 kk][8 ct][512]  frag-linear padded Wd_eff
#define BD_F  59392    // f32 [128] bd_eff zero-padded
#define WO_F  59520    // f32 [10][112] Wo_eff
#define BL_F  60640    // f32 [10] blog
#define MK_F  60650    // f32 [100] mask

__device__ __forceinline__ short f2bf(float f) {
    unsigned u = __builtin_bit_cast(unsigned, f);
    unsigned r = u + 0x7fffu + ((u >> 16) & 1u);   // RNE
    return (short)(r >> 16);
}

// ---------------- prep1: parallel exact fp32 gating + folded tables ----------------
__global__ __launch_bounds__(1024) void prep1_kernel(
                             const float* __restrict__ x,
                             const float* __restrict__ W_in,
                             const float* __restrict__ b_in,
                             const float* __restrict__ W_gate,
                             const float* __restrict__ b_gate,
                             const float* __restrict__ b_data,
                             const float* __restrict__ W_out,
                             const float* __restrict__ b_out,
                             float* __restrict__ out,
                             float* __restrict__ ws) {
    __shared__ float a0r0[SD];
    __shared__ float mask_l[SD];
    __shared__ float ao_l[NB];
    const int tid = threadIdx.x;

    // acts0 row 0: 8 threads per output c, k-split 98 each, shfl reduce
    if (tid < 800) {
        int c = tid >> 3, h = tid & 7;
        int s = c / DD, d = c % DD;
        const float* wcol = W_in + s * (N_IN * DD) + d;
        float acc = 0.f;
        int i0 = h * 98;
        #pragma unroll 14
        for (int i = i0; i < i0 + 98; ++i)
            acc += x[i] * wcol[i * DD];
        acc += __shfl_xor(acc, 1, 64);
        acc += __shfl_xor(acc, 2, 64);
        acc += __shfl_xor(acc, 4, 64);
        if (h == 0) a0r0[c] = fmaxf(acc + b_in[c], 0.f);
    }
    __syncthreads();

    if (tid < SD) {                      // gate[s][t] -> mask
        float g = b_gate[tid];
        int s = tid / DD;
        for (int d = 0; d < DD; ++d)
            g += a0r0[s * DD + d] * W_gate[tid * DD + d];
        mask_l[tid] = (g > 0.f) ? 1.f : 0.f;
    }
    __syncthreads();

    if (tid < NB) {
        float any = 0.f;
        for (int s = 0; s < NB; ++s) any = fmaxf(any, mask_l[s * DD + tid]);
        ao_l[tid] = any;
    }
    if (tid == 0) {
        float sum = 0.f;
        for (int i = 0; i < SD; ++i) sum += mask_l[i];
        out[(long)BATCH * N_OUTS] = sum / 20.0f;          // prob_open_gate
    }
    __syncthreads();

    if (tid < SD) ws[MK_F + tid] = mask_l[tid];

    for (int idx = tid; idx < 128; idx += blockDim.x) {    // bd_eff padded
        float v = 0.f;
        if (idx < SD) {
            int t = idx / DD, e = idx % DD;
            for (int s = 0; s < NB; ++s)
                v += mask_l[s * DD + t] * b_data[(s * NB + t) * DD + e];
        }
        ws[BD_F + idx] = v;
    }
    for (int idx = tid; idx < 10 * 112; idx += blockDim.x) {   // Wo_eff
        int o = idx / 112, te = idx % 112;
        float v = 0.f;
        if (te < SD) {
            int t = te / DD, e = te % DD;
            v = ao_l[t] * W_out[(t * DD + e) * N_OUTS + o];
        }
        ws[WO_F + idx] = v;
    }
    if (tid < N_OUTS) {                  // blog
        float v = 0.f;
        for (int t = 0; t < NB; ++t) v += ao_l[t] * b_out[t * N_OUTS + tid];
        ws[BL_F + tid] = v;
    }
}

// ---------------- prep2: bf16 fragment-linear weight tables (8-ct padded) ----------------
__global__ void prep2_kernel(const float* __restrict__ W_in,
                             const float* __restrict__ W_data,
                             float* __restrict__ ws) {
    short* wtf = (short*)(ws + WTF_F);
    short* wdf = (short*)(ws + WDF_F);
    const float* mask = ws + MK_F;
    const int n1 = 25 * 8 * 512;     // 102400
    const int n2 = 4 * 8 * 512;      // 16384
    for (int idx = blockIdx.x * blockDim.x + threadIdx.x; idx < n1 + n2;
         idx += gridDim.x * blockDim.x) {
        if (idx < n1) {
            int K = idx / 4096, rem = idx % 4096;
            int ct = rem / 512, l2 = rem % 512;
            int l = l2 >> 3, e = l2 & 7;
            int r = l & 15, g = l >> 4;
            int c = 16 * ct + r, k = K * 32 + g * 8 + e;
            float v = (c < SD && k < N_IN)
                          ? W_in[(c / DD) * (N_IN * DD) + k * DD + (c % DD)] : 0.f;
            wtf[idx] = f2bf(v);
        } else {
            int i2 = idx - n1;
            int kk = i2 / 4096, rem = i2 % 4096;
            int ct = rem / 512, l2 = rem % 512;
            int l = l2 >> 3, e = l2 & 7;
            int r = l & 15, g = l >> 4;
            int m = 16 * ct + r, k = kk * 32 + g * 8 + e;
            float v = 0.f;
            if (m < SD && k < SD) {
                int t = m / DD, eo = m % DD, s = k / DD, d = k % DD;
                v = mask[s * DD + t] * W_data[((s * NB + t) * DD + d) * DD + eo];
            }
            wdf[i2] = f2bf(v);
        }
    }
}

// ---- asm-pipelined phase 2 helpers (depth 3, no tied asm operands) ----
#define ISSUE_X(S, J) do {                                                     \
    const float* _pl;                                                          \
    if ((J) == 24 && g >= 2) _pl = xrow;  /* clamp: zero weights kill it */    \
    else                     _pl = xrow + (J) * 32 + g * 8;                    \
    asm volatile("global_load_dwordx4 %0, %1, off nt"                          \
                 : "=v"(xs[S][0]) : "v"(_pl) : "memory");                      \
    asm volatile("global_load_dwordx4 %0, %1, off nt"                          \
                 : "=v"(xs[S][1]) : "v"(_pl + 4) : "memory");                  \
} while (0)

#define ISSUE_AF(S, J) do {                                                    \
    _Pragma("unroll")                                                          \
    for (int ct = 0; ct < 7; ++ct) {                                           \
        const short* _pa = wtl + ((J) * 8 + ct) * 512;                         \
        asm volatile("global_load_dwordx4 %0, %1, off"                         \
                     : "=v"(afs[S][ct]) : "v"(_pa) : "memory");                \
    }                                                                          \
} while (0)

#define WAITV(CNT) do {                                                        \
    asm volatile("s_waitcnt vmcnt(" #CNT ")" ::: "memory");                    \
    __builtin_amdgcn_sched_barrier(0);                                         \
} while (0)

#define CONSUME(S) do {                                                        \
    union { unsigned u[4]; bf16x8 v; } _o;                                     \
    asm volatile("v_cvt_pk_bf16_f32 %0, %1, %2"                                \
                 : "=v"(_o.u[0]) : "v"(xs[S][0].x), "v"(xs[S][0].y));          \
    asm volatile("v_cvt_pk_bf16_f32 %0, %1, %2"                                \
                 : "=v"(_o.u[1]) : "v"(xs[S][0].z), "v"(xs[S][0].w));          \
    asm volatile("v_cvt_pk_bf16_f32 %0, %1, %2"                                \
                 : "=v"(_o.u[2]) : "v"(xs[S][1].x), "v"(xs[S][1].y));          \
    asm volatile("v_cvt_pk_bf16_f32 %0, %1, %2"                                \
                 : "=v"(_o.u[3]) : "v"(xs[S][1].z), "v"(xs[S][1].w));          \
    _Pragma("unroll")                                                          \
    for (int ct = 0; ct < 7; ++ct)                                             \
        acc[ct] = __builtin_amdgcn_mfma_f32_16x16x32_bf16(afs[S][ct], _o.v,    \
                                                          acc[ct], 0, 0, 0);  \
} while (0)

// ---------------- main: per-wave depth-3 asm pipeline, NT x loads, LDS tail ----------------
__global__ __launch_bounds__(256) void main_kernel(
        const float* __restrict__ x,
        const float* __restrict__ b_in,
        const float* __restrict__ ws,
        float* __restrict__ out) {
    __shared__ __align__(16) short a0b[64 * 136];   // [64 rows][136 bf16], stride 272 B
    __shared__ float WoL[10 * 116];                 // 116-padded rows
    __shared__ float bdL[112];
    __shared__ float biL[112];
    __shared__ float blL[16];

    const int tid  = threadIdx.x;
    const int w    = tid >> 6;
    const int lane = tid & 63;
    const int g    = lane >> 4;
    const int r    = lane & 15;
    const int lrow = w * 16 + r;
    const long grow = (long)blockIdx.x * 64 + lrow;

    const short* wtf = (const short*)(ws + WTF_F);
    const short* wdf = (const short*)(ws + WDF_F);
    const short* wtl = wtf + lane * 8;
    const float* xrow = x + grow * N_IN;

    // stage small tail tables to LDS (drained by the barrier -> vmcnt 0 at pipeline start)
    for (int idx = tid; idx < 10 * 112; idx += 256) {
        int o = idx / 112, te = idx % 112;
        WoL[o * 116 + te] = ws[WO_F + idx];
    }
    for (int idx = tid; idx < 112; idx += 256) {
        bdL[idx] = ws[BD_F + idx];
        biL[idx] = (idx < SD) ? b_in[idx] : 0.f;
    }
    if (tid < 10) blL[tid] = ws[BL_F + tid];
    __syncthreads();

    f32x4 acc[7];
    #pragma unroll
    for (int ct = 0; ct < 7; ++ct) acc[ct] = (f32x4){0.f, 0.f, 0.f, 0.f};

    float4 xs[3][2];
    bf16x8 afs[3][7];

    // prologue: steps 0,1,2 in flight (27 loads)
    ISSUE_X(0, 0); ISSUE_AF(0, 0);
    ISSUE_X(1, 1); ISSUE_AF(1, 1);
    ISSUE_X(2, 2); ISSUE_AF(2, 2);

    #pragma unroll
    for (int j = 0; j < 22; ++j) {
        const int S = j % 3;
        WAITV(18);              // step j done; steps j+1, j+2 (18 loads) in flight
        CONSUME(S);
        ISSUE_X(S, j + 3);
        ISSUE_AF(S, j + 3);
    }
    WAITV(18); CONSUME(1);      // step 22
    WAITV(9);  CONSUME(2);      // step 23
    WAITV(0);  CONSUME(0);      // step 24 (full drain)

    // bias + relu + cvt -> a0b row (bf16), cols 112..127 zeroed
    short* myrow = a0b + lrow * 136;
    #pragma unroll
    for (int ct = 0; ct < 7; ++ct) {
        int c0 = 16 * ct + 4 * g;
        float v0 = fmaxf(acc[ct][0] + biL[c0 + 0], 0.f);
        float v1 = fmaxf(acc[ct][1] + biL[c0 + 1], 0.f);
        float v2 = fmaxf(acc[ct][2] + biL[c0 + 2], 0.f);
        float v3 = fmaxf(acc[ct][3] + biL[c0 + 3], 0.f);
        unsigned p01, p23;
        asm("v_cvt_pk_bf16_f32 %0, %1, %2" : "=v"(p01) : "v"(v0), "v"(v1));
        asm("v_cvt_pk_bf16_f32 %0, %1, %2" : "=v"(p23) : "v"(v2), "v"(v3));
        *(uint2*)(myrow + c0) = make_uint2(p01, p23);
    }
    *(uint2*)(myrow + 112 + 4 * g) = make_uint2(0u, 0u);

    // ---- phase 3a: acts1 = relu(acts0 @ Wd^T + bd), MFMA K=128 (own rows, no barrier) ----
    f32x4 acc2[7];
    #pragma unroll
    for (int ct = 0; ct < 7; ++ct) acc2[ct] = (f32x4){0.f, 0.f, 0.f, 0.f};
    #pragma unroll
    for (int kk = 0; kk < 4; ++kk) {
        bf16x8 bfrag = *(const bf16x8*)(myrow + kk * 32 + g * 8);
        #pragma unroll
        for (int ct = 0; ct < 7; ++ct) {
            bf16x8 afrag = *(const bf16x8*)(wdf + (kk * 8 + ct) * 512 + lane * 8);
            acc2[ct] = __builtin_amdgcn_mfma_f32_16x16x32_bf16(afrag, bfrag, acc2[ct], 0, 0, 0);
        }
    }
    float a1r[28];
    #pragma unroll
    for (int ct = 0; ct < 7; ++ct) {
        #pragma unroll
        for (int j = 0; j < 4; ++j) {
            int te = 16 * ct + 4 * g + j;
            a1r[ct * 4 + j] = fmaxf(acc2[ct][j] + bdL[te], 0.f);
        }
    }

    // ---- phase 3b: logits = acts1 @ Wo_eff^T + blog (Wo from LDS); log_softmax ----
    float part[10];
    #pragma unroll
    for (int o = 0; o < 10; ++o) part[o] = 0.f;
    #pragma unroll
    for (int ct = 0; ct < 7; ++ct) {
        int te0 = 16 * ct + 4 * g;
        #pragma unroll
        for (int o = 0; o < 10; ++o) {
            float4 wv = *(const float4*)(WoL + o * 116 + te0);
            part[o] += a1r[ct * 4 + 0] * wv.x + a1r[ct * 4 + 1] * wv.y
                     + a1r[ct * 4 + 2] * wv.z + a1r[ct * 4 + 3] * wv.w;
        }
    }
    #pragma unroll
    for (int o = 0; o < 10; ++o) {
        part[o] += __shfl_xor(part[o], 16, 64);
        part[o] += __shfl_xor(part[o], 32, 64);
    }
    if (g == 0) {
        float lg[10];
        float m = -1e30f;
        #pragma unroll
        for (int o = 0; o < 10; ++o) {
            lg[o] = part[o] + blL[o];
            m = fmaxf(m, lg[o]);
        }
        float s = 0.f;
        #pragma unroll
        for (int o = 0; o < 10; ++o) s += expf(lg[o] - m);
        float z = m + logf(s);
        float* ob = out + grow * N_OUTS;
        #pragma unroll
        for (int q = 0; q < 5; ++q)
            *(float2*)(ob + 2 * q) = make_float2(lg[2 * q] - z, lg[2 * q + 1] - z);
    }
}

extern "C" void kernel_launch(void* const* d_in, const int* in_sizes, int n_in,
                              void* d_out, int out_size, void* d_ws, size_t ws_size,
                              hipStream_t stream) {
    const float* x      = (const float*)d_in[0];
    const float* W_in   = (const float*)d_in[1];
    const float* b_in   = (const float*)d_in[2];
    const float* W_gate = (const float*)d_in[3];
    const float* b_gate = (const float*)d_in[4];
    const float* W_data = (const float*)d_in[5];
    const float* b_data = (const float*)d_in[6];
    const float* W_out  = (const float*)d_in[7];
    const float* b_out  = (const float*)d_in[8];
    float* out = (float*)d_out;
    float* ws  = (float*)d_ws;

    prep1_kernel<<<1, 1024, 0, stream>>>(x, W_in, b_in, W_gate, b_gate,
                                         b_data, W_out, b_out, out, ws);
    prep2_kernel<<<256, 256, 0, stream>>>(W_in, W_data, ws);
    main_kernel<<<BATCH / 64, 256, 0, stream>>>(x, b_in, ws, out);
}